// Round 18
// baseline (1685.387 us; speedup 1.0000x reference)
//
#include <hip/hip_runtime.h>
#include <math.h>

#define B 16
#define S 256
#define H 768
#define NH 12
#define DH 64
#define DFF 3072
#define L 12
#define T 9
#define M (B*S)
#define LN_EPS 1e-12f
#define QKVS (3*H)
#define NCH 16   // CRF chunks per batch
#define MH ((size_t)M * H)

typedef __attribute__((ext_vector_type(8))) __bf16 bf16x8;
typedef __attribute__((ext_vector_type(8))) unsigned short u16x8;
typedef __attribute__((ext_vector_type(4))) unsigned short u16x4;
typedef __attribute__((ext_vector_type(4))) float f32x4;

__device__ __forceinline__ unsigned short f2bf(float f) {
    unsigned int u = __float_as_uint(f);
    unsigned int r = u + 0x7fffu + ((u >> 16) & 1u);
    return (unsigned short)(r >> 16);
}
__device__ __forceinline__ float bf2f(unsigned short h) {
    return __uint_as_float((unsigned int)h << 16);
}
// fast GELU: v * u/(u+1), u = e^{2y}, y = 0.79788456(v + 0.044715 v^3); |err| <= ~3e-3
__device__ __forceinline__ float fast_gelu(float v) {
    float y = 0.7978845608028654f * (v + 0.044715f * v * v * v);
    y = fminf(y, 40.0f);
    float u = exp2f(y * 2.8853900817779268f);   // e^{2y}
    return v * (u / (u + 1.0f));
}

// ---------------- Shared conversion tile: 32(k) x 128(n), 256 threads ----------------
// Reads 512B-contiguous rows of W (KxN f32), writes u16x8 segments of WT (NxK bf16).
__device__ __forceinline__ void convT_tile32x128(const float* __restrict__ Wp,
                                                 unsigned short* __restrict__ Tp,
                                                 int Kd, int Nd, int tilesN,
                                                 int f, int u, float (*tile)[132]) {
    const int n0 = (f % tilesN) << 7, k0 = (f / tilesN) << 5;
    const int r = u >> 5, c4 = (u & 31) << 2;
#pragma unroll
    for (int i = 0; i < 4; ++i) {
        const int row = r + (i << 3);
        *(float4*)&tile[row][c4] = *(const float4*)&Wp[(size_t)(k0 + row) * Nd + n0 + c4];
    }
    __syncthreads();
#pragma unroll
    for (int it = 0; it < 2; ++it) {
        const int idx = u + (it << 8);
        const int nr = idx >> 2, kc = (idx & 3) << 3;
        u16x8 o;
#pragma unroll
        for (int j = 0; j < 8; ++j) o[j] = f2bf(tile[kc + j][nr]);
        *(u16x8*)&Tp[(size_t)(n0 + nr) * Kd + k0 + kc] = o;
    }
}

// ---------------- Merged weight convert+transpose for the 4 HxH weights ----------------
// grid (144, 1, 4L): 144 = (H/128)*(H/32) tiles per matrix.
__global__ void convT4_kernel(const float* __restrict__ Wq, const float* __restrict__ Wk,
                              const float* __restrict__ Wv, const float* __restrict__ Wo,
                              unsigned short* __restrict__ wqkvT, unsigned short* __restrict__ woT) {
    __shared__ float tile[32][132];
    const int z = blockIdx.z;
    const int which = z / L, layer = z - which * L;
    const float* Wp = (which == 0 ? Wq : which == 1 ? Wk : which == 2 ? Wv : Wo)
                      + (size_t)layer * H * H;
    unsigned short* Tp = (which < 3)
        ? wqkvT + (size_t)layer * 3 * H * H + (size_t)which * H * H
        : woT + (size_t)layer * H * H;
    convT_tile32x128(Wp, Tp, H, H, H / 128, blockIdx.x, threadIdx.x, tile);
}

// ---------------- Merged FF weight convert+transpose: W1 (HxDFF) and W2 (DFFxH) ----------------
// grid (576, 1, 2L): W1 -> 24 n-tiles x 24 k-tiles; W2 -> 6 n-tiles x 96 k-tiles (both 576).
__global__ void convTFF_kernel(const float* __restrict__ W1, const float* __restrict__ W2,
                               unsigned short* __restrict__ w1T, unsigned short* __restrict__ w2T) {
    __shared__ float tile[32][132];
    const int z = blockIdx.z;
    const int which = z / L, layer = z - which * L;
    if (which == 0) {
        convT_tile32x128(W1 + (size_t)layer * H * DFF, w1T + (size_t)layer * H * DFF,
                         H, DFF, DFF / 128, blockIdx.x, threadIdx.x, tile);
    } else {
        convT_tile32x128(W2 + (size_t)layer * H * DFF, w2T + (size_t)layer * H * DFF,
                         DFF, H, H / 128, blockIdx.x, threadIdx.x, tile);
    }
}

// ---------------- Concat QKV biases per layer: [L][2304] ----------------
__global__ void biascat_kernel(const float* __restrict__ bq, const float* __restrict__ bk,
                               const float* __restrict__ bv, float* __restrict__ out) {
    int idx = blockIdx.x * 256 + threadIdx.x;
    if (idx >= L * QKVS) return;
    int l = idx / QKVS, c = idx % QKVS;
    float v = (c < H) ? bq[l * H + c] : (c < 2 * H) ? bk[l * H + c - H] : bv[l * H + c - 2 * H];
    out[idx] = v;
}

// ---------------- Embedding + LayerNorm (192 threads, float4 in, bf16 out) ----------------
__global__ void embed_ln_kernel(const int* __restrict__ x,
                                const float* __restrict__ word_emb,
                                const float* __restrict__ pos_emb,
                                const float* __restrict__ type_emb,
                                const float* __restrict__ g,
                                const float* __restrict__ bta,
                                unsigned short* __restrict__ hb) {
    const int row = blockIdx.x;
    const int s = row % S;
    const int tok = x[row];
    const int t = threadIdx.x;     // 192
    const int c = t << 2;
    const float4 wv = *(const float4*)&word_emb[(size_t)tok * H + c];
    const float4 pv = *(const float4*)&pos_emb[s * H + c];
    const float4 tv = *(const float4*)&type_emb[c];
    float v[4] = {wv.x + pv.x + tv.x, wv.y + pv.y + tv.y, wv.z + pv.z + tv.z, wv.w + pv.w + tv.w};
    float s1 = v[0] + v[1] + v[2] + v[3];
    float s2 = v[0]*v[0] + v[1]*v[1] + v[2]*v[2] + v[3]*v[3];
#pragma unroll
    for (int o = 32; o; o >>= 1) { s1 += __shfl_xor(s1, o); s2 += __shfl_xor(s2, o); }
    __shared__ float ws[3][2];
    const int w = t >> 6, l = t & 63;
    if (l == 0) { ws[w][0] = s1; ws[w][1] = s2; }
    __syncthreads();
    const float S1 = ws[0][0] + ws[1][0] + ws[2][0];
    const float S2 = ws[0][1] + ws[1][1] + ws[2][1];
    const float mean = S1 * (1.0f / H);
    const float var = fmaxf(S2 * (1.0f / H) - mean * mean, 0.f);
    const float inv = rsqrtf(var + LN_EPS);
    const float4 gv = *(const float4*)&g[c];
    const float4 bv = *(const float4*)&bta[c];
    u16x4 ob;
    ob[0] = f2bf((v[0] - mean) * inv * gv.x + bv.x);
    ob[1] = f2bf((v[1] - mean) * inv * gv.y + bv.y);
    ob[2] = f2bf((v[2] - mean) * inv * gv.z + bv.z);
    ob[3] = f2bf((v[3] - mean) * inv * gv.w + bv.w);
    *(u16x4*)&hb[(size_t)row * H + c] = ob;
}

// ---------------- Residual + LayerNorm (bf16 stream; sums NS stacked delta partials) ----------------
template<int NS>
__global__ void residual_ln_kernel(unsigned short* __restrict__ hb,
                                   const unsigned short* __restrict__ delta,
                                   const float* __restrict__ g,
                                   const float* __restrict__ bta) {
    const int row = blockIdx.x;
    const int t = threadIdx.x;     // 192
    const int c = t << 2;
    const size_t base = (size_t)row * H + c;
    const u16x4 hv4 = *(const u16x4*)&hb[base];
    float v[4] = {bf2f(hv4[0]), bf2f(hv4[1]), bf2f(hv4[2]), bf2f(hv4[3])};
#pragma unroll
    for (int sgm = 0; sgm < NS; ++sgm) {
        const u16x4 dv4 = *(const u16x4*)&delta[sgm * MH + base];
#pragma unroll
        for (int j = 0; j < 4; ++j) v[j] += bf2f(dv4[j]);
    }
    float s1 = v[0] + v[1] + v[2] + v[3];
    float s2 = v[0]*v[0] + v[1]*v[1] + v[2]*v[2] + v[3]*v[3];
#pragma unroll
    for (int o = 32; o; o >>= 1) { s1 += __shfl_xor(s1, o); s2 += __shfl_xor(s2, o); }
    __shared__ float ws[3][2];
    const int w = t >> 6, l = t & 63;
    if (l == 0) { ws[w][0] = s1; ws[w][1] = s2; }
    __syncthreads();
    const float S1 = ws[0][0] + ws[1][0] + ws[2][0];
    const float S2 = ws[0][1] + ws[1][1] + ws[2][1];
    const float mean = S1 * (1.0f / H);
    const float var = fmaxf(S2 * (1.0f / H) - mean * mean, 0.f);
    const float inv = rsqrtf(var + LN_EPS);
    const float4 gv = *(const float4*)&g[c];
    const float4 bv = *(const float4*)&bta[c];
    u16x4 ob;
    ob[0] = f2bf((v[0] - mean) * inv * gv.x + bv.x);
    ob[1] = f2bf((v[1] - mean) * inv * gv.y + bv.y);
    ob[2] = f2bf((v[2] - mean) * inv * gv.z + bv.z);
    ob[3] = f2bf((v[3] - mean) * inv * gv.w + bv.w);
    *(u16x4*)&hb[base] = ob;
}

#define LSTR 72

// ---------------- bf16 MFMA GEMM: C = A @ WT^T (+ bias on split 0) ----------------
// Tile (MR*32) x (NR*32), 4 waves (2x2). Reg-staged padded LDS, BK=64, 3 blocks/CU.
// K-split via blockIdx.z. XCD-aware swizzle over the (x,y) plane.
template<int ACT, int MR, int NR>
__global__ __launch_bounds__(256, 3)
void gemm_bf16(const unsigned short* __restrict__ A,
               const unsigned short* __restrict__ WT,
               const float* __restrict__ bias,
               unsigned short* __restrict__ Cb,
               int Ksub, int Kfull, int N, size_t splitStride) {
    __shared__ unsigned short lA[MR * 32 * LSTR];
    __shared__ unsigned short lB[NR * 32 * LSTR];
    const int tid = threadIdx.x;
    const int z = blockIdx.z;
    const int gx = gridDim.x;
    const int nb = gx * gridDim.y;
    int f = blockIdx.y * gx + blockIdx.x;
    f = (f & 7) * (nb >> 3) + (f >> 3);
    const int m0 = (f / gx) * (MR * 32), n0 = (f % gx) * (NR * 32);
    const int l = tid & 63, w = tid >> 6;
    const int wr = w >> 1, wc = w & 1;
    const int lr = l & 15, kg = l >> 4;

    const int srow = tid >> 3, scol = (tid & 7) << 3;
    const int kOff = z * Ksub;
    const unsigned short* gA = A + (size_t)(m0 + srow) * Kfull + kOff + scol;
    const unsigned short* gB = WT + (size_t)(n0 + srow) * Kfull + kOff + scol;

    f32x4 acc[MR][NR];
#pragma unroll
    for (int i = 0; i < MR; ++i)
#pragma unroll
        for (int j = 0; j < NR; ++j) acc[i][j] = (f32x4){0.f, 0.f, 0.f, 0.f};

    u16x8 ra[MR], rb[NR];
#pragma unroll
    for (int p = 0; p < MR; ++p) ra[p] = *(const u16x8*)(gA + (size_t)p * 32 * Kfull);
#pragma unroll
    for (int p = 0; p < NR; ++p) rb[p] = *(const u16x8*)(gB + (size_t)p * 32 * Kfull);

    for (int kt = 0; kt < Ksub; kt += 64) {
#pragma unroll
        for (int p = 0; p < MR; ++p)
            *(u16x8*)&lA[(srow + p * 32) * LSTR + scol] = ra[p];
#pragma unroll
        for (int p = 0; p < NR; ++p)
            *(u16x8*)&lB[(srow + p * 32) * LSTR + scol] = rb[p];
        __syncthreads();
        if (kt + 64 < Ksub) {
#pragma unroll
            for (int p = 0; p < MR; ++p) ra[p] = *(const u16x8*)(gA + (size_t)p * 32 * Kfull + kt + 64);
#pragma unroll
            for (int p = 0; p < NR; ++p) rb[p] = *(const u16x8*)(gB + (size_t)p * 32 * Kfull + kt + 64);
        }
#pragma unroll
        for (int ks = 0; ks < 2; ++ks) {
            bf16x8 af[MR], bfr[NR];
#pragma unroll
            for (int m = 0; m < MR; ++m)
                af[m] = *(const bf16x8*)&lA[(wr * (MR * 16) + (m << 4) + lr) * LSTR + ks * 32 + (kg << 3)];
#pragma unroll
            for (int n = 0; n < NR; ++n)
                bfr[n] = *(const bf16x8*)&lB[((wc * (NR * 16)) + (n << 4) + lr) * LSTR + ks * 32 + (kg << 3)];
#pragma unroll
            for (int m = 0; m < MR; ++m)
#pragma unroll
                for (int n = 0; n < NR; ++n)
                    acc[m][n] = __builtin_amdgcn_mfma_f32_16x16x32_bf16(af[m], bfr[n], acc[m][n], 0, 0, 0);
        }
        __syncthreads();
    }

    unsigned short* Cz = Cb + (size_t)z * splitStride;
    const int rbase = m0 + wr * (MR * 16) + (kg << 2);
    const int cbase = n0 + wc * (NR * 16) + lr;
#pragma unroll
    for (int m = 0; m < MR; ++m) {
#pragma unroll
        for (int n = 0; n < NR; ++n) {
            const int col = cbase + (n << 4);
            const float bv = (z == 0) ? bias[col] : 0.f;
#pragma unroll
            for (int j = 0; j < 4; ++j) {
                const int row = rbase + (m << 4) + j;
                float v = acc[m][n][j] + bv;
                if (ACT == 1) v = fast_gelu(v);
                Cz[(size_t)row * N + col] = f2bf(v);
            }
        }
    }
}

// ---------------- MFMA attention: block = (b, h, 128-q-half); V transposed in-LDS ----------------
__global__ __launch_bounds__(256, 2)
void attn_mfma(const unsigned short* __restrict__ qkv,
               unsigned short* __restrict__ ctxb) {
    __shared__ unsigned short Ks[256 * 72];
    __shared__ unsigned short Vt[64 * 264];
    __shared__ unsigned short Ps[4][16 * 72];

    // XCD swizzle: 384 blocks -> 48 contiguous logical blocks per XCD
    int f = blockIdx.x;
    f = (f & 7) * 48 + (f >> 3);
    const int half = f & 1;
    const int hh = (f >> 1) % NH;
    const int b = f / (2 * NH);
    const int t = threadIdx.x;
    const int l = t & 63, w = t >> 6;
    const int l15 = l & 15, g = l >> 4;

    {
        const int c0 = (t & 7) << 3;
        int r = t >> 3;
#pragma unroll
        for (int it = 0; it < 8; ++it, r += 32) {
            u16x8 kv = *(const u16x8*)&qkv[(size_t)(b * S + r) * QKVS + H + hh * 64 + c0];
            *(u16x8*)&Ks[r * 72 + c0] = kv;
        }
    }
    {
        const int d0 = (t & 7) << 3;
        int s = t >> 3;
#pragma unroll
        for (int it = 0; it < 8; ++it, s += 32) {
            u16x8 vv = *(const u16x8*)&qkv[(size_t)(b * S + s) * QKVS + 2 * H + hh * 64 + d0];
#pragma unroll
            for (int j = 0; j < 8; ++j) {
                int d = d0 + j;
                Vt[d * 264 + (s ^ (((d >> 3) & 7) << 3))] = vv[j];
            }
        }
    }
    __syncthreads();

    unsigned short* ps = Ps[w];
#pragma unroll
    for (int qi = 0; qi < 2; ++qi) {
        const int qrow = half * 128 + qi * 64 + w * 16 + l15;
        const unsigned short* qp = &qkv[(size_t)(b * S + qrow) * QKVS + hh * 64 + g * 8];
        bf16x8 aq0 = *(const bf16x8*)qp;
        bf16x8 aq1 = *(const bf16x8*)(qp + 32);

        f32x4 acc[16];
#pragma unroll
        for (int n = 0; n < 16; ++n) acc[n] = (f32x4){0.f, 0.f, 0.f, 0.f};
        __builtin_amdgcn_s_setprio(1);
#pragma unroll
        for (int n = 0; n < 16; ++n) {
            const unsigned short* kp = &Ks[(n * 16 + l15) * 72 + g * 8];
            bf16x8 b0 = *(const bf16x8*)kp;
            bf16x8 b1 = *(const bf16x8*)(kp + 32);
            acc[n] = __builtin_amdgcn_mfma_f32_16x16x32_bf16(aq0, b0, acc[n], 0, 0, 0);
            acc[n] = __builtin_amdgcn_mfma_f32_16x16x32_bf16(aq1, b1, acc[n], 0, 0, 0);
        }
        __builtin_amdgcn_s_setprio(0);

        float inv[4];
#pragma unroll
        for (int j = 0; j < 4; ++j) {
            float mx = acc[0][j];
#pragma unroll
            for (int n = 1; n < 16; ++n) mx = fmaxf(mx, acc[n][j]);
            mx = fmaxf(mx, __shfl_xor(mx, 1));
            mx = fmaxf(mx, __shfl_xor(mx, 2));
            mx = fmaxf(mx, __shfl_xor(mx, 4));
            mx = fmaxf(mx, __shfl_xor(mx, 8));
            float sum = 0.f;
#pragma unroll
            for (int n = 0; n < 16; ++n) {
                float e = exp2f((acc[n][j] - mx) * 0.18033688011112042f);
                acc[n][j] = e;
                sum += e;
            }
            sum += __shfl_xor(sum, 1);
            sum += __shfl_xor(sum, 2);
            sum += __shfl_xor(sum, 4);
            sum += __shfl_xor(sum, 8);
            inv[j] = 1.0f / sum;
        }

        f32x4 cacc[4];
#pragma unroll
        for (int nd = 0; nd < 4; ++nd) cacc[nd] = (f32x4){0.f, 0.f, 0.f, 0.f};
#pragma unroll
        for (int c = 0; c < 4; ++c) {
#pragma unroll
            for (int nl = 0; nl < 4; ++nl) {
                int n = c * 4 + nl;
#pragma unroll
                for (int j = 0; j < 4; ++j)
                    ps[(g * 4 + j) * 72 + nl * 16 + l15] = f2bf(acc[n][j]);
            }
            bf16x8 pa0 = *(const bf16x8*)&ps[l15 * 72 + g * 8];
            bf16x8 pa1 = *(const bf16x8*)&ps[l15 * 72 + 32 + g * 8];
            __builtin_amdgcn_s_setprio(1);
#pragma unroll
            for (int nd = 0; nd < 4; ++nd) {
                const int d = nd * 16 + l15;
                const int swz = ((d >> 3) & 7) << 3;
                const unsigned short* vp0 = &Vt[d * 264 + ((c * 64 + g * 8) ^ swz)];
                const unsigned short* vp1 = &Vt[d * 264 + ((c * 64 + 32 + g * 8) ^ swz)];
                bf16x8 v0 = *(const bf16x8*)vp0;
                bf16x8 v1 = *(const bf16x8*)vp1;
                cacc[nd] = __builtin_amdgcn_mfma_f32_16x16x32_bf16(pa0, v0, cacc[nd], 0, 0, 0);
                cacc[nd] = __builtin_amdgcn_mfma_f32_16x16x32_bf16(pa1, v1, cacc[nd], 0, 0, 0);
            }
            __builtin_amdgcn_s_setprio(0);
        }

#pragma unroll
        for (int nd = 0; nd < 4; ++nd)
#pragma unroll
            for (int j = 0; j < 4; ++j) {
                int qr = half * 128 + qi * 64 + w * 16 + g * 4 + j;
                ctxb[(size_t)(b * S + qr) * H + hh * 64 + nd * 16 + l15] = f2bf(cacc[nd][j] * inv[j]);
            }
    }
}

// ---------------- Classifier: one wave per row (bf16 h) ----------------
__global__ void clf_kernel(const unsigned short* __restrict__ hb,
                           const float* __restrict__ W,
                           const float* __restrict__ bias,
                           float* __restrict__ logits) {
    const int row = blockIdx.x * 4 + (threadIdx.x >> 6);
    const int l = threadIdx.x & 63;
    const unsigned short* hp = hb + (size_t)row * H;
    float acc[T] = {};
#pragma unroll
    for (int i = 0; i < 12; ++i) {
        const int k = l + (i << 6);
        const float x = bf2f(hp[k]);
        const float* wp = &W[k * T];
#pragma unroll
        for (int n = 0; n < T; ++n) acc[n] += x * wp[n];
    }
#pragma unroll
    for (int o = 32; o; o >>= 1)
#pragma unroll
        for (int n = 0; n < T; ++n) acc[n] += __shfl_xor(acc[n], o);
    if (l < T) logits[(size_t)row * T + l] = acc[l] + bias[l];
}

// ---------------- CRF chunk: 9x9 transfer-matrix product over 16 steps (log-semiring) ----------------
__global__ void crf_chunk_kernel(const float* __restrict__ logits,
                                 const int* __restrict__ target,
                                 const float* __restrict__ trans,
                                 float* __restrict__ Tc) {
    const int blk = blockIdx.x;
    const int b = blk >> 4, c = blk & 15;
    const int t = threadIdx.x;     // 128
    const int i = t / 9, j = t - i * 9;
    const bool act = t < 81;
    __shared__ float Tb[2][81];
    const float* lg = logits + (size_t)b * S * T;
    const int* tg = target + b * S;
    const float K2 = 1.44269504088896340736f;
    const float IK = 0.69314718055994530942f;

    float trc[T];
    if (act) {
#pragma unroll
        for (int k = 0; k < T; ++k) trc[k] = trans[k * T + j];
        Tb[0][t] = (i == j) ? 0.f : -1e30f;
    }
    __syncthreads();

    int p = 0;
    const int s0 = c * 16 + 1;
    const int s1 = (c == 15) ? S : (s0 + 16);
    for (int s = s0; s < s1; ++s) {
        if (tg[s] > -1) {
            if (act) {
                const float em = lg[s * T + j];
                float v[T];
#pragma unroll
                for (int k = 0; k < T; ++k) v[k] = Tb[p][i * 9 + k] + trc[k];
                float mx = fmaxf(v[0], v[1]);
                mx = fmaxf(mx, fmaxf(v[2], v[3]));
                mx = fmaxf(mx, fmaxf(v[4], v[5]));
                mx = fmaxf(mx, fmaxf(v[6], v[7]));
                mx = fmaxf(mx, v[8]);
                float sum = 0.f;
#pragma unroll
                for (int k = 0; k < T; ++k) sum += exp2f((v[k] - mx) * K2);
                Tb[p ^ 1][t] = mx + IK * log2f(sum) + em;
            }
            __syncthreads();
            p ^= 1;
        }
    }
    if (act) Tc[(size_t)blk * 81 + t] = Tb[p][t];
}

// ---------------- CRF final: numerator + chunk combine + denominator + mean, one block ----------------
__global__ __launch_bounds__(1024)
void crf_final_kernel(const float* __restrict__ logits,
                      const int* __restrict__ target,
                      const float* __restrict__ start,
                      const float* __restrict__ trans,
                      const float* __restrict__ endv,
                      const float* __restrict__ Tc,
                      float* __restrict__ out) {
    const int t = threadIdx.x;   // 1024 = 16 waves; wave = batch
    const int b = t >> 6, l = t & 63;
    const float* lg = logits + (size_t)b * S * T;
    const int* tg = target + b * S;
    const float K2 = 1.44269504088896340736f;
    const float IK = 0.69314718055994530942f;

    float pnum = 0.f; int pcnt = 0;
#pragma unroll
    for (int c = 0; c < 4; ++c) {
        const int s = 1 + l + (c << 6);
        if (s < S) {
            const int tcur = tg[s], tprev = tg[s - 1];
            const bool m = tcur > -1;
            const int tag = m ? tcur : 0;
            const int ptag = (tprev > -1) ? tprev : 0;
            if (m) { pnum += trans[ptag * T + tag] + lg[s * T + tag]; pcnt += 1; }
        }
    }
#pragma unroll
    for (int o = 32; o; o >>= 1) { pnum += __shfl_xor(pnum, o); pcnt += __shfl_xor(pcnt, o); }

    const int jj = (l < T) ? l : 0;
    float a = start[jj] + lg[jj];
    for (int c = 0; c < NCH; ++c) {
        const float* Tm = Tc + ((size_t)(b * NCH + c)) * 81;
        float v[T];
#pragma unroll
        for (int i2 = 0; i2 < T; ++i2) v[i2] = __shfl(a, i2) + Tm[i2 * 9 + jj];
        float mx = fmaxf(v[0], v[1]);
        mx = fmaxf(mx, fmaxf(v[2], v[3]));
        mx = fmaxf(mx, fmaxf(v[4], v[5]));
        mx = fmaxf(mx, fmaxf(v[6], v[7]));
        mx = fmaxf(mx, v[8]);
        float sum = 0.f;
#pragma unroll
        for (int k = 0; k < T; ++k) sum += exp2f((v[k] - mx) * K2);
        a = mx + IK * log2f(sum);
    }

    float val = (l < T) ? (a + endv[jj]) : -1e30f;
    float mx = val;
#pragma unroll
    for (int o = 8; o; o >>= 1) mx = fmaxf(mx, __shfl_xor(mx, o));
    float sm = (l < T) ? exp2f((val - mx) * K2) : 0.f;
#pragma unroll
    for (int o = 8; o; o >>= 1) sm += __shfl_xor(sm, o);
    const float denom = mx + IK * log2f(sm);

    __shared__ float part[16];
    if (l == 0) {
        const bool m0 = tg[0] > -1;
        const int tag0 = m0 ? tg[0] : 0;
        const int cnt = pcnt + (m0 ? 1 : 0);
        int lastIdx = cnt - 1; if (lastIdx < 0) lastIdx = 0;
        const int lt = tg[lastIdx];
        const int lastTag = (lt > -1) ? lt : 0;
        const float num = start[tag0] + lg[tag0] + pnum + endv[lastTag];
        part[b] = num - denom;
    }
    __syncthreads();
    if (t == 0) {
        float s = 0.f;
#pragma unroll
        for (int i = 0; i < 16; ++i) s += part[i];
        out[0] = -s * (1.0f / 16.0f);
    }
}

// ---------------- Host launch ----------------
extern "C" void kernel_launch(void* const* d_in, const int* in_sizes, int n_in,
                              void* d_out, int out_size, void* d_ws, size_t ws_size,
                              hipStream_t stream) {
    const int*   x        = (const int*)d_in[0];
    const int*   target   = (const int*)d_in[1];
    const float* word_emb = (const float*)d_in[2];
    const float* pos_emb  = (const float*)d_in[3];
    const float* type_emb = (const float*)d_in[4];
    const float* emb_ln_g = (const float*)d_in[5];
    const float* emb_ln_b = (const float*)d_in[6];
    const float* Wq = (const float*)d_in[7];
    const float* bq = (const float*)d_in[8];
    const float* Wk = (const float*)d_in[9];
    const float* bk = (const float*)d_in[10];
    const float* Wv = (const float*)d_in[11];
    const float* bv = (const float*)d_in[12];
    const float* Wo = (const float*)d_in[13];
    const float* bo = (const float*)d_in[14];
    const float* ln1_g = (const float*)d_in[15];
    const float* ln1_b = (const float*)d_in[16];
    const float* W1 = (const float*)d_in[17];
    const float* b1 = (const float*)d_in[18];
    const float* W2 = (const float*)d_in[19];
    const float* b2 = (const float*)d_in[20];
    const float* ln2_g = (const float*)d_in[21];
    const float* ln2_b = (const float*)d_in[22];
    const float* clf_W = (const float*)d_in[23];
    const float* clf_b = (const float*)d_in[24];
    const float* crf_start = (const float*)d_in[25];
    const float* crf_trans = (const float*)d_in[26];
    const float* crf_end   = (const float*)d_in[27];

    char* ws = (char*)d_ws;
    size_t off = 0;
    auto alloc = [&](size_t bytes) { void* p = ws + off; off += (bytes + 255) & ~255ull; return p; };

    unsigned short* wqkvT = (unsigned short*)alloc((size_t)L * 3 * H * H * 2);
    unsigned short* woT   = (unsigned short*)alloc((size_t)L * H * H * 2);
    unsigned short* w1T   = (unsigned short*)alloc((size_t)L * H * DFF * 2);
    unsigned short* w2T   = (unsigned short*)alloc((size_t)L * H * DFF * 2);
    float*          bcat  = (float*)alloc((size_t)L * QKVS * 4);
    unsigned short* hb    = (unsigned short*)alloc(MH * 2);
    unsigned short* qkvb  = (unsigned short*)alloc((size_t)M * QKVS * 2);
    unsigned short* ctxb  = (unsigned short*)alloc(MH * 2);
    unsigned short* gob   = (unsigned short*)alloc(4 * MH * 2);   // K-split partials
    unsigned short* ffb   = (unsigned short*)alloc((size_t)M * DFF * 2);
    float*          logits = (float*)alloc((size_t)M * T * 4);
    float*          Tcbuf  = (float*)alloc((size_t)B * NCH * 81 * 4);

    convT4_kernel<<<dim3((H / 128) * (H / 32), 1, 4 * L), 256, 0, stream>>>(Wq, Wk, Wv, Wo, wqkvT, woT);
    convTFF_kernel<<<dim3((DFF / 128) * (H / 32), 1, 2 * L), 256, 0, stream>>>(W1, W2, w1T, w2T);
    biascat_kernel<<<(L * QKVS + 255) / 256, 256, 0, stream>>>(bq, bk, bv, bcat);

    embed_ln_kernel<<<M, 192, 0, stream>>>(x, word_emb, pos_emb, type_emb, emb_ln_g, emb_ln_b, hb);

    const dim3 gQKV(QKVS / 96, M / 128, 1);   // 24 x 32      (MR=4, NR=3 -> 768 blocks = 3/CU)
    const dim3 gFF1(DFF / 128, M / 128, 1);   // 24 x 32      (MR=4, NR=4 -> 768 blocks)
    const dim3 gWo (H / 128, M / 64, 2);      // 6 x 64 x 2   (MR=2, NR=4, K-split 2 -> 768)
    const dim3 gFF2(H / 128, M / 64, 2);      // 6 x 64 x 2   (MR=2, NR=4, K-split 2 -> 768, Ksub=1536)

    for (int l = 0; l < L; ++l) {
        gemm_bf16<0, 4, 3><<<gQKV, 256, 0, stream>>>(hb, wqkvT + (size_t)l * 3 * H * H, bcat + l * QKVS,
                                                     qkvb, H, H, QKVS, 0);
        attn_mfma<<<B * NH * 2, 256, 0, stream>>>(qkvb, ctxb);
        gemm_bf16<0, 2, 4><<<gWo, 256, 0, stream>>>(ctxb, woT + (size_t)l * H * H, bo + l * H,
                                                    gob, H / 2, H, H, MH);
        residual_ln_kernel<2><<<M, 192, 0, stream>>>(hb, gob, ln1_g + l * H, ln1_b + l * H);
        gemm_bf16<1, 4, 4><<<gFF1, 256, 0, stream>>>(hb, w1T + (size_t)l * H * DFF, b1 + l * DFF,
                                                     ffb, H, H, DFF, 0);
        gemm_bf16<0, 2, 4><<<gFF2, 256, 0, stream>>>(ffb, w2T + (size_t)l * H * DFF, b2 + l * H,
                                                     gob, DFF / 2, DFF, H, MH);
        residual_ln_kernel<2><<<M, 192, 0, stream>>>(hb, gob, ln2_g + l * H, ln2_b + l * H);
    }

    clf_kernel<<<M / 4, 256, 0, stream>>>(hb, clf_W, clf_b, logits);
    crf_chunk_kernel<<<B * NCH, 128, 0, stream>>>(logits, target, crf_trans, Tcbuf);
    crf_final_kernel<<<1, 1024, 0, stream>>>(logits, target, crf_start, crf_trans, crf_end, Tcbuf, (float*)d_out);
}

// Round 19
// 1675.757 us; speedup vs baseline: 1.0057x; 1.0057x over previous
//
#include <hip/hip_runtime.h>
#include <math.h>

#define B 16
#define S 256
#define H 768
#define NH 12
#define DH 64
#define DFF 3072
#define L 12
#define T 9
#define M (B*S)
#define LN_EPS 1e-12f
#define QKVS (3*H)
#define NCH 16   // CRF chunks per batch
#define MH ((size_t)M * H)

typedef __attribute__((ext_vector_type(8))) __bf16 bf16x8;
typedef __attribute__((ext_vector_type(8))) unsigned short u16x8;
typedef __attribute__((ext_vector_type(4))) unsigned short u16x4;
typedef __attribute__((ext_vector_type(4))) float f32x4;

__device__ __forceinline__ unsigned short f2bf(float f) {
    unsigned int u = __float_as_uint(f);
    unsigned int r = u + 0x7fffu + ((u >> 16) & 1u);
    return (unsigned short)(r >> 16);
}
__device__ __forceinline__ float bf2f(unsigned short h) {
    return __uint_as_float((unsigned int)h << 16);
}
// fast GELU: v * u/(u+1), u = e^{2y}, y = 0.79788456(v + 0.044715 v^3); |err| <= ~3e-3
__device__ __forceinline__ float fast_gelu(float v) {
    float y = 0.7978845608028654f * (v + 0.044715f * v * v * v);
    y = fminf(y, 40.0f);
    float u = exp2f(y * 2.8853900817779268f);   // e^{2y}
    return v * (u / (u + 1.0f));
}

// ---------------- Shared conversion tile: 64(k) x 64(n), 256 threads ----------------
// Reads 256B-contiguous rows of W (KxN f32); writes 128B-contiguous u16x8 rows of WT (NxK bf16).
// LDS stride 67 floats: transpose-read banks = (3*row+col)%32 -> ~2-way (free).
#define CSTR 67
__device__ __forceinline__ void convT_tile64(const float* __restrict__ Wp,
                                             unsigned short* __restrict__ Tp,
                                             int Kd, int Nd, int tilesN,
                                             int f, int u, float* __restrict__ tile) {
    const int n0 = (f % tilesN) << 6, k0 = (f / tilesN) << 6;
    const int r = u >> 4, cc = (u & 15) << 2;
#pragma unroll
    for (int i = 0; i < 4; ++i) {
        const int row = r + (i << 4);
        const float4 v = *(const float4*)&Wp[(size_t)(k0 + row) * Nd + n0 + cc];
        float* dst = &tile[row * CSTR + cc];
        dst[0] = v.x; dst[1] = v.y; dst[2] = v.z; dst[3] = v.w;
    }
    __syncthreads();
#pragma unroll
    for (int it = 0; it < 2; ++it) {
        const int idx = u + (it << 8);
        const int nr = idx >> 3, kc = (idx & 7) << 3;
        u16x8 o;
#pragma unroll
        for (int j = 0; j < 8; ++j) o[j] = f2bf(tile[(kc + j) * CSTR + nr]);
        *(u16x8*)&Tp[(size_t)(n0 + nr) * Kd + k0 + kc] = o;
    }
}

// ---------------- Merged weight convert+transpose for the 4 HxH weights ----------------
// grid (144, 1, 4L): 144 = (H/64)*(H/64) tiles per matrix.
__global__ void convT4_kernel(const float* __restrict__ Wq, const float* __restrict__ Wk,
                              const float* __restrict__ Wv, const float* __restrict__ Wo,
                              unsigned short* __restrict__ wqkvT, unsigned short* __restrict__ woT) {
    __shared__ float tile[64 * CSTR];
    const int z = blockIdx.z;
    const int which = z / L, layer = z - which * L;
    const float* Wp = (which == 0 ? Wq : which == 1 ? Wk : which == 2 ? Wv : Wo)
                      + (size_t)layer * H * H;
    unsigned short* Tp = (which < 3)
        ? wqkvT + (size_t)layer * 3 * H * H + (size_t)which * H * H
        : woT + (size_t)layer * H * H;
    convT_tile64(Wp, Tp, H, H, H / 64, blockIdx.x, threadIdx.x, tile);
}

// ---------------- Merged FF weight convert+transpose: W1 (HxDFF) and W2 (DFFxH) ----------------
// grid (576, 1, 2L): W1 -> 12 k-tiles x 48 n-tiles; W2 -> 48 k-tiles x 12 n-tiles (both 576).
__global__ void convTFF_kernel(const float* __restrict__ W1, const float* __restrict__ W2,
                               unsigned short* __restrict__ w1T, unsigned short* __restrict__ w2T) {
    __shared__ float tile[64 * CSTR];
    const int z = blockIdx.z;
    const int which = z / L, layer = z - which * L;
    if (which == 0) {
        convT_tile64(W1 + (size_t)layer * H * DFF, w1T + (size_t)layer * H * DFF,
                     H, DFF, DFF / 64, blockIdx.x, threadIdx.x, tile);
    } else {
        convT_tile64(W2 + (size_t)layer * H * DFF, w2T + (size_t)layer * H * DFF,
                     DFF, H, H / 64, blockIdx.x, threadIdx.x, tile);
    }
}

// ---------------- Concat QKV biases per layer: [L][2304] ----------------
__global__ void biascat_kernel(const float* __restrict__ bq, const float* __restrict__ bk,
                               const float* __restrict__ bv, float* __restrict__ out) {
    int idx = blockIdx.x * 256 + threadIdx.x;
    if (idx >= L * QKVS) return;
    int l = idx / QKVS, c = idx % QKVS;
    float v = (c < H) ? bq[l * H + c] : (c < 2 * H) ? bk[l * H + c - H] : bv[l * H + c - 2 * H];
    out[idx] = v;
}

// ---------------- Embedding + LayerNorm (192 threads, float4 in, bf16 out) ----------------
__global__ void embed_ln_kernel(const int* __restrict__ x,
                                const float* __restrict__ word_emb,
                                const float* __restrict__ pos_emb,
                                const float* __restrict__ type_emb,
                                const float* __restrict__ g,
                                const float* __restrict__ bta,
                                unsigned short* __restrict__ hb) {
    const int row = blockIdx.x;
    const int s = row % S;
    const int tok = x[row];
    const int t = threadIdx.x;     // 192
    const int c = t << 2;
    const float4 wv = *(const float4*)&word_emb[(size_t)tok * H + c];
    const float4 pv = *(const float4*)&pos_emb[s * H + c];
    const float4 tv = *(const float4*)&type_emb[c];
    float v[4] = {wv.x + pv.x + tv.x, wv.y + pv.y + tv.y, wv.z + pv.z + tv.z, wv.w + pv.w + tv.w};
    float s1 = v[0] + v[1] + v[2] + v[3];
    float s2 = v[0]*v[0] + v[1]*v[1] + v[2]*v[2] + v[3]*v[3];
#pragma unroll
    for (int o = 32; o; o >>= 1) { s1 += __shfl_xor(s1, o); s2 += __shfl_xor(s2, o); }
    __shared__ float ws[3][2];
    const int w = t >> 6, l = t & 63;
    if (l == 0) { ws[w][0] = s1; ws[w][1] = s2; }
    __syncthreads();
    const float S1 = ws[0][0] + ws[1][0] + ws[2][0];
    const float S2 = ws[0][1] + ws[1][1] + ws[2][1];
    const float mean = S1 * (1.0f / H);
    const float var = fmaxf(S2 * (1.0f / H) - mean * mean, 0.f);
    const float inv = rsqrtf(var + LN_EPS);
    const float4 gv = *(const float4*)&g[c];
    const float4 bv = *(const float4*)&bta[c];
    u16x4 ob;
    ob[0] = f2bf((v[0] - mean) * inv * gv.x + bv.x);
    ob[1] = f2bf((v[1] - mean) * inv * gv.y + bv.y);
    ob[2] = f2bf((v[2] - mean) * inv * gv.z + bv.z);
    ob[3] = f2bf((v[3] - mean) * inv * gv.w + bv.w);
    *(u16x4*)&hb[(size_t)row * H + c] = ob;
}

// ---------------- Residual + LayerNorm (bf16 stream; sums NS stacked delta partials) ----------------
template<int NS>
__global__ void residual_ln_kernel(unsigned short* __restrict__ hb,
                                   const unsigned short* __restrict__ delta,
                                   const float* __restrict__ g,
                                   const float* __restrict__ bta) {
    const int row = blockIdx.x;
    const int t = threadIdx.x;     // 192
    const int c = t << 2;
    const size_t base = (size_t)row * H + c;
    const u16x4 hv4 = *(const u16x4*)&hb[base];
    float v[4] = {bf2f(hv4[0]), bf2f(hv4[1]), bf2f(hv4[2]), bf2f(hv4[3])};
#pragma unroll
    for (int sgm = 0; sgm < NS; ++sgm) {
        const u16x4 dv4 = *(const u16x4*)&delta[sgm * MH + base];
#pragma unroll
        for (int j = 0; j < 4; ++j) v[j] += bf2f(dv4[j]);
    }
    float s1 = v[0] + v[1] + v[2] + v[3];
    float s2 = v[0]*v[0] + v[1]*v[1] + v[2]*v[2] + v[3]*v[3];
#pragma unroll
    for (int o = 32; o; o >>= 1) { s1 += __shfl_xor(s1, o); s2 += __shfl_xor(s2, o); }
    __shared__ float ws[3][2];
    const int w = t >> 6, l = t & 63;
    if (l == 0) { ws[w][0] = s1; ws[w][1] = s2; }
    __syncthreads();
    const float S1 = ws[0][0] + ws[1][0] + ws[2][0];
    const float S2 = ws[0][1] + ws[1][1] + ws[2][1];
    const float mean = S1 * (1.0f / H);
    const float var = fmaxf(S2 * (1.0f / H) - mean * mean, 0.f);
    const float inv = rsqrtf(var + LN_EPS);
    const float4 gv = *(const float4*)&g[c];
    const float4 bv = *(const float4*)&bta[c];
    u16x4 ob;
    ob[0] = f2bf((v[0] - mean) * inv * gv.x + bv.x);
    ob[1] = f2bf((v[1] - mean) * inv * gv.y + bv.y);
    ob[2] = f2bf((v[2] - mean) * inv * gv.z + bv.z);
    ob[3] = f2bf((v[3] - mean) * inv * gv.w + bv.w);
    *(u16x4*)&hb[base] = ob;
}

#define LSTR 72

// ---------------- bf16 MFMA GEMM: C = A @ WT^T (+ bias on split 0) ----------------
// Tile (MR*32) x (NR*32), 4 waves (2x2). Reg-staged padded LDS, BK=64, 3 blocks/CU.
// K-split via blockIdx.z. XCD-aware swizzle over the (x,y) plane.
template<int ACT, int MR, int NR>
__global__ __launch_bounds__(256, 3)
void gemm_bf16(const unsigned short* __restrict__ A,
               const unsigned short* __restrict__ WT,
               const float* __restrict__ bias,
               unsigned short* __restrict__ Cb,
               int Ksub, int Kfull, int N, size_t splitStride) {
    __shared__ unsigned short lA[MR * 32 * LSTR];
    __shared__ unsigned short lB[NR * 32 * LSTR];
    const int tid = threadIdx.x;
    const int z = blockIdx.z;
    const int gx = gridDim.x;
    const int nb = gx * gridDim.y;
    int f = blockIdx.y * gx + blockIdx.x;
    f = (f & 7) * (nb >> 3) + (f >> 3);
    const int m0 = (f / gx) * (MR * 32), n0 = (f % gx) * (NR * 32);
    const int l = tid & 63, w = tid >> 6;
    const int wr = w >> 1, wc = w & 1;
    const int lr = l & 15, kg = l >> 4;

    const int srow = tid >> 3, scol = (tid & 7) << 3;
    const int kOff = z * Ksub;
    const unsigned short* gA = A + (size_t)(m0 + srow) * Kfull + kOff + scol;
    const unsigned short* gB = WT + (size_t)(n0 + srow) * Kfull + kOff + scol;

    f32x4 acc[MR][NR];
#pragma unroll
    for (int i = 0; i < MR; ++i)
#pragma unroll
        for (int j = 0; j < NR; ++j) acc[i][j] = (f32x4){0.f, 0.f, 0.f, 0.f};

    u16x8 ra[MR], rb[NR];
#pragma unroll
    for (int p = 0; p < MR; ++p) ra[p] = *(const u16x8*)(gA + (size_t)p * 32 * Kfull);
#pragma unroll
    for (int p = 0; p < NR; ++p) rb[p] = *(const u16x8*)(gB + (size_t)p * 32 * Kfull);

    for (int kt = 0; kt < Ksub; kt += 64) {
#pragma unroll
        for (int p = 0; p < MR; ++p)
            *(u16x8*)&lA[(srow + p * 32) * LSTR + scol] = ra[p];
#pragma unroll
        for (int p = 0; p < NR; ++p)
            *(u16x8*)&lB[(srow + p * 32) * LSTR + scol] = rb[p];
        __syncthreads();
        if (kt + 64 < Ksub) {
#pragma unroll
            for (int p = 0; p < MR; ++p) ra[p] = *(const u16x8*)(gA + (size_t)p * 32 * Kfull + kt + 64);
#pragma unroll
            for (int p = 0; p < NR; ++p) rb[p] = *(const u16x8*)(gB + (size_t)p * 32 * Kfull + kt + 64);
        }
#pragma unroll
        for (int ks = 0; ks < 2; ++ks) {
            bf16x8 af[MR], bfr[NR];
#pragma unroll
            for (int m = 0; m < MR; ++m)
                af[m] = *(const bf16x8*)&lA[(wr * (MR * 16) + (m << 4) + lr) * LSTR + ks * 32 + (kg << 3)];
#pragma unroll
            for (int n = 0; n < NR; ++n)
                bfr[n] = *(const bf16x8*)&lB[((wc * (NR * 16)) + (n << 4) + lr) * LSTR + ks * 32 + (kg << 3)];
#pragma unroll
            for (int m = 0; m < MR; ++m)
#pragma unroll
                for (int n = 0; n < NR; ++n)
                    acc[m][n] = __builtin_amdgcn_mfma_f32_16x16x32_bf16(af[m], bfr[n], acc[m][n], 0, 0, 0);
        }
        __syncthreads();
    }

    unsigned short* Cz = Cb + (size_t)z * splitStride;
    const int rbase = m0 + wr * (MR * 16) + (kg << 2);
    const int cbase = n0 + wc * (NR * 16) + lr;
#pragma unroll
    for (int m = 0; m < MR; ++m) {
#pragma unroll
        for (int n = 0; n < NR; ++n) {
            const int col = cbase + (n << 4);
            const float bv = (z == 0) ? bias[col] : 0.f;
#pragma unroll
            for (int j = 0; j < 4; ++j) {
                const int row = rbase + (m << 4) + j;
                float v = acc[m][n][j] + bv;
                if (ACT == 1) v = fast_gelu(v);
                Cz[(size_t)row * N + col] = f2bf(v);
            }
        }
    }
}

// ---------------- MFMA attention: block = (b, h, 128-q-half); V transposed in-LDS ----------------
__global__ __launch_bounds__(256, 2)
void attn_mfma(const unsigned short* __restrict__ qkv,
               unsigned short* __restrict__ ctxb) {
    __shared__ unsigned short Ks[256 * 72];
    __shared__ unsigned short Vt[64 * 264];
    __shared__ unsigned short Ps[4][16 * 72];

    // XCD swizzle: 384 blocks -> 48 contiguous logical blocks per XCD
    int f = blockIdx.x;
    f = (f & 7) * 48 + (f >> 3);
    const int half = f & 1;
    const int hh = (f >> 1) % NH;
    const int b = f / (2 * NH);
    const int t = threadIdx.x;
    const int l = t & 63, w = t >> 6;
    const int l15 = l & 15, g = l >> 4;

    {
        const int c0 = (t & 7) << 3;
        int r = t >> 3;
#pragma unroll
        for (int it = 0; it < 8; ++it, r += 32) {
            u16x8 kv = *(const u16x8*)&qkv[(size_t)(b * S + r) * QKVS + H + hh * 64 + c0];
            *(u16x8*)&Ks[r * 72 + c0] = kv;
        }
    }
    {
        const int d0 = (t & 7) << 3;
        int s = t >> 3;
#pragma unroll
        for (int it = 0; it < 8; ++it, s += 32) {
            u16x8 vv = *(const u16x8*)&qkv[(size_t)(b * S + s) * QKVS + 2 * H + hh * 64 + d0];
#pragma unroll
            for (int j = 0; j < 8; ++j) {
                int d = d0 + j;
                Vt[d * 264 + (s ^ (((d >> 3) & 7) << 3))] = vv[j];
            }
        }
    }
    __syncthreads();

    unsigned short* ps = Ps[w];
#pragma unroll
    for (int qi = 0; qi < 2; ++qi) {
        const int qrow = half * 128 + qi * 64 + w * 16 + l15;
        const unsigned short* qp = &qkv[(size_t)(b * S + qrow) * QKVS + hh * 64 + g * 8];
        bf16x8 aq0 = *(const bf16x8*)qp;
        bf16x8 aq1 = *(const bf16x8*)(qp + 32);

        f32x4 acc[16];
#pragma unroll
        for (int n = 0; n < 16; ++n) acc[n] = (f32x4){0.f, 0.f, 0.f, 0.f};
        __builtin_amdgcn_s_setprio(1);
#pragma unroll
        for (int n = 0; n < 16; ++n) {
            const unsigned short* kp = &Ks[(n * 16 + l15) * 72 + g * 8];
            bf16x8 b0 = *(const bf16x8*)kp;
            bf16x8 b1 = *(const bf16x8*)(kp + 32);
            acc[n] = __builtin_amdgcn_mfma_f32_16x16x32_bf16(aq0, b0, acc[n], 0, 0, 0);
            acc[n] = __builtin_amdgcn_mfma_f32_16x16x32_bf16(aq1, b1, acc[n], 0, 0, 0);
        }
        __builtin_amdgcn_s_setprio(0);

        float inv[4];
#pragma unroll
        for (int j = 0; j < 4; ++j) {
            float mx = acc[0][j];
#pragma unroll
            for (int n = 1; n < 16; ++n) mx = fmaxf(mx, acc[n][j]);
            mx = fmaxf(mx, __shfl_xor(mx, 1));
            mx = fmaxf(mx, __shfl_xor(mx, 2));
            mx = fmaxf(mx, __shfl_xor(mx, 4));
            mx = fmaxf(mx, __shfl_xor(mx, 8));
            float sum = 0.f;
#pragma unroll
            for (int n = 0; n < 16; ++n) {
                float e = exp2f((acc[n][j] - mx) * 0.18033688011112042f);
                acc[n][j] = e;
                sum += e;
            }
            sum += __shfl_xor(sum, 1);
            sum += __shfl_xor(sum, 2);
            sum += __shfl_xor(sum, 4);
            sum += __shfl_xor(sum, 8);
            inv[j] = 1.0f / sum;
        }

        f32x4 cacc[4];
#pragma unroll
        for (int nd = 0; nd < 4; ++nd) cacc[nd] = (f32x4){0.f, 0.f, 0.f, 0.f};
#pragma unroll
        for (int c = 0; c < 4; ++c) {
#pragma unroll
            for (int nl = 0; nl < 4; ++nl) {
                int n = c * 4 + nl;
#pragma unroll
                for (int j = 0; j < 4; ++j)
                    ps[(g * 4 + j) * 72 + nl * 16 + l15] = f2bf(acc[n][j]);
            }
            bf16x8 pa0 = *(const bf16x8*)&ps[l15 * 72 + g * 8];
            bf16x8 pa1 = *(const bf16x8*)&ps[l15 * 72 + 32 + g * 8];
            __builtin_amdgcn_s_setprio(1);
#pragma unroll
            for (int nd = 0; nd < 4; ++nd) {
                const int d = nd * 16 + l15;
                const int swz = ((d >> 3) & 7) << 3;
                const unsigned short* vp0 = &Vt[d * 264 + ((c * 64 + g * 8) ^ swz)];
                const unsigned short* vp1 = &Vt[d * 264 + ((c * 64 + 32 + g * 8) ^ swz)];
                bf16x8 v0 = *(const bf16x8*)vp0;
                bf16x8 v1 = *(const bf16x8*)vp1;
                cacc[nd] = __builtin_amdgcn_mfma_f32_16x16x32_bf16(pa0, v0, cacc[nd], 0, 0, 0);
                cacc[nd] = __builtin_amdgcn_mfma_f32_16x16x32_bf16(pa1, v1, cacc[nd], 0, 0, 0);
            }
            __builtin_amdgcn_s_setprio(0);
        }

#pragma unroll
        for (int nd = 0; nd < 4; ++nd)
#pragma unroll
            for (int j = 0; j < 4; ++j) {
                int qr = half * 128 + qi * 64 + w * 16 + g * 4 + j;
                ctxb[(size_t)(b * S + qr) * H + hh * 64 + nd * 16 + l15] = f2bf(cacc[nd][j] * inv[j]);
            }
    }
}

// ---------------- Classifier: one wave per row (bf16 h) ----------------
__global__ void clf_kernel(const unsigned short* __restrict__ hb,
                           const float* __restrict__ W,
                           const float* __restrict__ bias,
                           float* __restrict__ logits) {
    const int row = blockIdx.x * 4 + (threadIdx.x >> 6);
    const int l = threadIdx.x & 63;
    const unsigned short* hp = hb + (size_t)row * H;
    float acc[T] = {};
#pragma unroll
    for (int i = 0; i < 12; ++i) {
        const int k = l + (i << 6);
        const float x = bf2f(hp[k]);
        const float* wp = &W[k * T];
#pragma unroll
        for (int n = 0; n < T; ++n) acc[n] += x * wp[n];
    }
#pragma unroll
    for (int o = 32; o; o >>= 1)
#pragma unroll
        for (int n = 0; n < T; ++n) acc[n] += __shfl_xor(acc[n], o);
    if (l < T) logits[(size_t)row * T + l] = acc[l] + bias[l];
}

// ---------------- CRF chunk: 9x9 transfer-matrix product over 16 steps (log-semiring) ----------------
__global__ void crf_chunk_kernel(const float* __restrict__ logits,
                                 const int* __restrict__ target,
                                 const float* __restrict__ trans,
                                 float* __restrict__ Tc) {
    const int blk = blockIdx.x;
    const int b = blk >> 4, c = blk & 15;
    const int t = threadIdx.x;     // 128
    const int i = t / 9, j = t - i * 9;
    const bool act = t < 81;
    __shared__ float Tb[2][81];
    const float* lg = logits + (size_t)b * S * T;
    const int* tg = target + b * S;
    const float K2 = 1.44269504088896340736f;
    const float IK = 0.69314718055994530942f;

    float trc[T];
    if (act) {
#pragma unroll
        for (int k = 0; k < T; ++k) trc[k] = trans[k * T + j];
        Tb[0][t] = (i == j) ? 0.f : -1e30f;
    }
    __syncthreads();

    int p = 0;
    const int s0 = c * 16 + 1;
    const int s1 = (c == 15) ? S : (s0 + 16);
    for (int s = s0; s < s1; ++s) {
        if (tg[s] > -1) {
            if (act) {
                const float em = lg[s * T + j];
                float v[T];
#pragma unroll
                for (int k = 0; k < T; ++k) v[k] = Tb[p][i * 9 + k] + trc[k];
                float mx = fmaxf(v[0], v[1]);
                mx = fmaxf(mx, fmaxf(v[2], v[3]));
                mx = fmaxf(mx, fmaxf(v[4], v[5]));
                mx = fmaxf(mx, fmaxf(v[6], v[7]));
                mx = fmaxf(mx, v[8]);
                float sum = 0.f;
#pragma unroll
                for (int k = 0; k < T; ++k) sum += exp2f((v[k] - mx) * K2);
                Tb[p ^ 1][t] = mx + IK * log2f(sum) + em;
            }
            __syncthreads();
            p ^= 1;
        }
    }
    if (act) Tc[(size_t)blk * 81 + t] = Tb[p][t];
}

// ---------------- CRF final: numerator + chunk combine + denominator + mean, one block ----------------
__global__ __launch_bounds__(1024)
void crf_final_kernel(const float* __restrict__ logits,
                      const int* __restrict__ target,
                      const float* __restrict__ start,
                      const float* __restrict__ trans,
                      const float* __restrict__ endv,
                      const float* __restrict__ Tc,
                      float* __restrict__ out) {
    const int t = threadIdx.x;   // 1024 = 16 waves; wave = batch
    const int b = t >> 6, l = t & 63;
    const float* lg = logits + (size_t)b * S * T;
    const int* tg = target + b * S;
    const float K2 = 1.44269504088896340736f;
    const float IK = 0.69314718055994530942f;

    float pnum = 0.f; int pcnt = 0;
#pragma unroll
    for (int c = 0; c < 4; ++c) {
        const int s = 1 + l + (c << 6);
        if (s < S) {
            const int tcur = tg[s], tprev = tg[s - 1];
            const bool m = tcur > -1;
            const int tag = m ? tcur : 0;
            const int ptag = (tprev > -1) ? tprev : 0;
            if (m) { pnum += trans[ptag * T + tag] + lg[s * T + tag]; pcnt += 1; }
        }
    }
#pragma unroll
    for (int o = 32; o; o >>= 1) { pnum += __shfl_xor(pnum, o); pcnt += __shfl_xor(pcnt, o); }

    const int jj = (l < T) ? l : 0;
    float a = start[jj] + lg[jj];
    for (int c = 0; c < NCH; ++c) {
        const float* Tm = Tc + ((size_t)(b * NCH + c)) * 81;
        float v[T];
#pragma unroll
        for (int i2 = 0; i2 < T; ++i2) v[i2] = __shfl(a, i2) + Tm[i2 * 9 + jj];
        float mx = fmaxf(v[0], v[1]);
        mx = fmaxf(mx, fmaxf(v[2], v[3]));
        mx = fmaxf(mx, fmaxf(v[4], v[5]));
        mx = fmaxf(mx, fmaxf(v[6], v[7]));
        mx = fmaxf(mx, v[8]);
        float sum = 0.f;
#pragma unroll
        for (int k = 0; k < T; ++k) sum += exp2f((v[k] - mx) * K2);
        a = mx + IK * log2f(sum);
    }

    float val = (l < T) ? (a + endv[jj]) : -1e30f;
    float mx = val;
#pragma unroll
    for (int o = 8; o; o >>= 1) mx = fmaxf(mx, __shfl_xor(mx, o));
    float sm = (l < T) ? exp2f((val - mx) * K2) : 0.f;
#pragma unroll
    for (int o = 8; o; o >>= 1) sm += __shfl_xor(sm, o);
    const float denom = mx + IK * log2f(sm);

    __shared__ float part[16];
    if (l == 0) {
        const bool m0 = tg[0] > -1;
        const int tag0 = m0 ? tg[0] : 0;
        const int cnt = pcnt + (m0 ? 1 : 0);
        int lastIdx = cnt - 1; if (lastIdx < 0) lastIdx = 0;
        const int lt = tg[lastIdx];
        const int lastTag = (lt > -1) ? lt : 0;
        const float num = start[tag0] + lg[tag0] + pnum + endv[lastTag];
        part[b] = num - denom;
    }
    __syncthreads();
    if (t == 0) {
        float s = 0.f;
#pragma unroll
        for (int i = 0; i < 16; ++i) s += part[i];
        out[0] = -s * (1.0f / 16.0f);
    }
}

// ---------------- Host launch ----------------
extern "C" void kernel_launch(void* const* d_in, const int* in_sizes, int n_in,
                              void* d_out, int out_size, void* d_ws, size_t ws_size,
                              hipStream_t stream) {
    const int*   x        = (const int*)d_in[0];
    const int*   target   = (const int*)d_in[1];
    const float* word_emb = (const float*)d_in[2];
    const float* pos_emb  = (const float*)d_in[3];
    const float* type_emb = (const float*)d_in[4];
    const float* emb_ln_g = (const float*)d_in[5];
    const float* emb_ln_b = (const float*)d_in[6];
    const float* Wq = (const float*)d_in[7];
    const float* bq = (const float*)d_in[8];
    const float* Wk = (const float*)d_in[9];
    const float* bk = (const float*)d_in[10];
    const float* Wv = (const float*)d_in[11];
    const float* bv = (const float*)d_in[12];
    const float* Wo = (const float*)d_in[13];
    const float* bo = (const float*)d_in[14];
    const float* ln1_g = (const float*)d_in[15];
    const float* ln1_b = (const float*)d_in[16];
    const float* W1 = (const float*)d_in[17];
    const float* b1 = (const float*)d_in[18];
    const float* W2 = (const float*)d_in[19];
    const float* b2 = (const float*)d_in[20];
    const float* ln2_g = (const float*)d_in[21];
    const float* ln2_b = (const float*)d_in[22];
    const float* clf_W = (const float*)d_in[23];
    const float* clf_b = (const float*)d_in[24];
    const float* crf_start = (const float*)d_in[25];
    const float* crf_trans = (const float*)d_in[26];
    const float* crf_end   = (const float*)d_in[27];

    char* ws = (char*)d_ws;
    size_t off = 0;
    auto alloc = [&](size_t bytes) { void* p = ws + off; off += (bytes + 255) & ~255ull; return p; };

    unsigned short* wqkvT = (unsigned short*)alloc((size_t)L * 3 * H * H * 2);
    unsigned short* woT   = (unsigned short*)alloc((size_t)L * H * H * 2);
    unsigned short* w1T   = (unsigned short*)alloc((size_t)L * H * DFF * 2);
    unsigned short* w2T   = (unsigned short*)alloc((size_t)L * H * DFF * 2);
    float*          bcat  = (float*)alloc((size_t)L * QKVS * 4);
    unsigned short* hb    = (unsigned short*)alloc(MH * 2);
    unsigned short* qkvb  = (unsigned short*)alloc((size_t)M * QKVS * 2);
    unsigned short* ctxb  = (unsigned short*)alloc(MH * 2);
    unsigned short* gob   = (unsigned short*)alloc(4 * MH * 2);   // K-split partials
    unsigned short* ffb   = (unsigned short*)alloc((size_t)M * DFF * 2);
    float*          logits = (float*)alloc((size_t)M * T * 4);
    float*          Tcbuf  = (float*)alloc((size_t)B * NCH * 81 * 4);

    convT4_kernel<<<dim3((H / 64) * (H / 64), 1, 4 * L), 256, 0, stream>>>(Wq, Wk, Wv, Wo, wqkvT, woT);
    convTFF_kernel<<<dim3((H / 64) * (DFF / 64), 1, 2 * L), 256, 0, stream>>>(W1, W2, w1T, w2T);
    biascat_kernel<<<(L * QKVS + 255) / 256, 256, 0, stream>>>(bq, bk, bv, bcat);

    embed_ln_kernel<<<M, 192, 0, stream>>>(x, word_emb, pos_emb, type_emb, emb_ln_g, emb_ln_b, hb);

    const dim3 gQKV(QKVS / 96, M / 128, 1);   // 24 x 32      (MR=4, NR=3 -> 768 blocks = 3/CU)
    const dim3 gFF1(DFF / 128, M / 128, 1);   // 24 x 32      (MR=4, NR=4 -> 768 blocks)
    const dim3 gWo (H / 128, M / 64, 2);      // 6 x 64 x 2   (MR=2, NR=4, K-split 2 -> 768)
    const dim3 gFF2(H / 128, M / 64, 2);      // 6 x 64 x 2   (MR=2, NR=4, K-split 2 -> 768, Ksub=1536)

    for (int l = 0; l < L; ++l) {
        gemm_bf16<0, 4, 3><<<gQKV, 256, 0, stream>>>(hb, wqkvT + (size_t)l * 3 * H * H, bcat + l * QKVS,
                                                     qkvb, H, H, QKVS, 0);
        attn_mfma<<<B * NH * 2, 256, 0, stream>>>(qkvb, ctxb);
        gemm_bf16<0, 2, 4><<<gWo, 256, 0, stream>>>(ctxb, woT + (size_t)l * H * H, bo + l * H,
                                                    gob, H / 2, H, H, MH);
        residual_ln_kernel<2><<<M, 192, 0, stream>>>(hb, gob, ln1_g + l * H, ln1_b + l * H);
        gemm_bf16<1, 4, 4><<<gFF1, 256, 0, stream>>>(hb, w1T + (size_t)l * H * DFF, b1 + l * DFF,
                                                     ffb, H, H, DFF, 0);
        gemm_bf16<0, 2, 4><<<gFF2, 256, 0, stream>>>(ffb, w2T + (size_t)l * H * DFF, b2 + l * H,
                                                     gob, DFF / 2, DFF, H, MH);
        residual_ln_kernel<2><<<M, 192, 0, stream>>>(hb, gob, ln2_g + l * H, ln2_b + l * H);
    }

    clf_kernel<<<M / 4, 256, 0, stream>>>(hb, clf_W, clf_b, logits);
    crf_chunk_kernel<<<B * NCH, 128, 0, stream>>>(logits, target, crf_trans, Tcbuf);
    crf_final_kernel<<<1, 1024, 0, stream>>>(logits, target, crf_start, crf_trans, crf_end, Tcbuf, (float*)d_out);
}